// Round 1
// baseline (589.899 us; speedup 1.0000x reference)
//
#include <hip/hip_runtime.h>
#include <stdint.h>

typedef __bf16 bf16;
typedef __bf16 bf16x8 __attribute__((ext_vector_type(8)));
typedef __bf16 bf16x4 __attribute__((ext_vector_type(4)));
typedef float  f32x4  __attribute__((ext_vector_type(4)));

#define T_SEQ  2048
#define NHEAD  16
#define DHEAD  128
#define DMODEL 2048
#define NQKV   3072   // 2048 Q | 512 K | 512 V per row

__device__ __forceinline__ void gload_lds16(const void* g, void* l) {
  __builtin_amdgcn_global_load_lds(
      (const __attribute__((address_space(1))) uint32_t*)g,
      (__attribute__((address_space(3))) uint32_t*)l, 16, 0, 0);
}

// ---------------- fp32 -> bf16 cast (x) ----------------
__global__ void k_cvt(const float* __restrict__ in, bf16* __restrict__ out) {
  int i = (blockIdx.x * 256 + threadIdx.x) * 4;
  float4 v = *(const float4*)(in + i);
  bf16x4 o = { (bf16)v.x, (bf16)v.y, (bf16)v.z, (bf16)v.w };
  *(bf16x4*)(out + i) = o;
}

// ---------------- W (K x N fp32) -> WT (N x K bf16) ----------------
__global__ __launch_bounds__(256) void k_twt(const float* __restrict__ W,
                                             bf16* __restrict__ WT, int K, int N) {
  __shared__ float t[64][65];
  int k0 = blockIdx.x * 64, n0 = blockIdx.y * 64;
  int r4 = threadIdx.x >> 6, c = threadIdx.x & 63;
#pragma unroll
  for (int i = 0; i < 16; i++) {
    int r = i * 4 + r4;
    t[r][c] = W[(size_t)(k0 + r) * N + n0 + c];
  }
  __syncthreads();
#pragma unroll
  for (int i = 0; i < 16; i++) {
    int r = i * 4 + r4;
    WT[(size_t)(n0 + r) * K + k0 + c] = (bf16)t[c][r];
  }
}

// ---------------- GEMM: C[M,N] = A[M,K] * BT[N,K]^T  (m97 structure) ----------------
template<bool F32OUT>
__global__ __launch_bounds__(256) void k_gemm(const bf16* __restrict__ A,
                                              const bf16* __restrict__ BT,
                                              void* __restrict__ C,
                                              int M, int N, int K) {
  __shared__ __align__(16) bf16 As[128 * 64];
  __shared__ __align__(16) bf16 Bs[128 * 64];
  const int m0 = blockIdx.x * 128, n0 = blockIdx.y * 128;
  const int tid = threadIdx.x;
  const int lane = tid & 63, w = tid >> 6;
  const int wr = w >> 1, wc = w & 1;
  const int l15 = lane & 15, lg = lane >> 4;
  f32x4 acc[4][4] = {};

  // staging geometry: wave w stages chunks c=w*4+i ; chunk = 8 rows x 128B
  const int rA = w * 32 + (lane >> 3);     // + i*8
  const int cA = (lane & 7) * 8;           // element col within 64
  const bf16* gA = A  + (size_t)(m0 + rA) * K + cA;
  const bf16* gB = BT + (size_t)(n0 + rA) * K + cA;

  for (int k0 = 0; k0 < K; k0 += 64) {
    __syncthreads();
#pragma unroll
    for (int i = 0; i < 4; i++) {
      gload_lds16(gA + (size_t)i * 8 * K + k0, As + (w * 4 + i) * 512);
      gload_lds16(gB + (size_t)i * 8 * K + k0, Bs + (w * 4 + i) * 512);
    }
    __syncthreads();
#pragma unroll
    for (int kk = 0; kk < 2; kk++) {
      bf16x8 af[4], bfr[4];
#pragma unroll
      for (int m = 0; m < 4; m++)
        af[m] = *(const bf16x8*)(As + (wr * 64 + m * 16 + l15) * 64 + kk * 32 + lg * 8);
#pragma unroll
      for (int n = 0; n < 4; n++)
        bfr[n] = *(const bf16x8*)(Bs + (wc * 64 + n * 16 + l15) * 64 + kk * 32 + lg * 8);
#pragma unroll
      for (int m = 0; m < 4; m++)
#pragma unroll
        for (int n = 0; n < 4; n++)
          acc[m][n] = __builtin_amdgcn_mfma_f32_16x16x32_bf16(af[m], bfr[n], acc[m][n], 0, 0, 0);
    }
  }
  const int r0 = m0 + wr * 64 + lg * 4;
  const int c0 = n0 + wc * 64 + l15;
#pragma unroll
  for (int m = 0; m < 4; m++)
#pragma unroll
    for (int n = 0; n < 4; n++)
#pragma unroll
      for (int i = 0; i < 4; i++) {
        size_t idx = (size_t)(r0 + m * 16 + i) * N + (c0 + n * 16);
        if (F32OUT) ((float*)C)[idx] = acc[m][n][i];
        else        ((bf16*)C)[idx]  = (bf16)acc[m][n][i];
      }
}

// ---------------- in-place RoPE on QKV cols [0,2560) ----------------
__global__ void k_rope(bf16* __restrict__ QKV) {
  const float L2B = 0.20762050593046007f;  // log2(10000)/64
  int tid = blockIdx.x * 256 + threadIdx.x;       // 4096*320 threads
  int row = tid / 320;
  int c8 = (tid - row * 320) * 8;
  int t = row & (T_SEQ - 1);
  bf16* p = QKV + (size_t)row * NQKV + c8;
  bf16x8 v = *(const bf16x8*)p;
  int ib = (c8 & 127) >> 1;
  bf16x8 o;
#pragma unroll
  for (int m = 0; m < 4; m++) {
    float inv = exp2f(-(float)(ib + m) * L2B);
    float ang = (float)t * inv;
    float cs, sn;
    __sincosf(ang, &sn, &cs);
    float x1 = (float)v[2 * m], x2 = (float)v[2 * m + 1];
    o[2 * m]     = (bf16)(x1 * cs - x2 * sn);
    o[2 * m + 1] = (bf16)(x1 * sn + x2 * cs);
  }
  *(bf16x8*)p = o;
}

// ---------------- flash attention (causal, GQA) ----------------
__global__ __launch_bounds__(256) void k_flash(const bf16* __restrict__ QKV,
                                               bf16* __restrict__ AO) {
  __shared__ __align__(16) bf16 Ks[64 * 128];      // XOR-swizzled rows of 256B
  __shared__ __align__(16) bf16 Vt[128][72];       // V transposed [d][kv]
  __shared__ __align__(16) bf16 Ps[4][16][72];     // per-wave P tile
  const int qt = blockIdx.x;
  const int bh = blockIdx.y;
  const int b = bh >> 4, h = bh & 15, kvh = h >> 2;
  const int tid = threadIdx.x, lane = tid & 63, w = tid >> 6;
  const int l15 = lane & 15, lg = lane >> 4;
  const float scale = 0.08838834764831845f;        // 1/sqrt(128)

  // Q fragments in registers (A-operand: row = lane&15, k = kk*32 + lg*8 + j)
  const size_t qoff = (size_t)(b * T_SEQ + qt * 64 + w * 16 + l15) * NQKV + h * DHEAD;
  bf16x8 qreg[4];
#pragma unroll
  for (int kk = 0; kk < 4; kk++)
    qreg[kk] = *(const bf16x8*)(QKV + qoff + kk * 32 + lg * 8);

  f32x4 o[8] = {};
  float mrow[4] = {-1e30f, -1e30f, -1e30f, -1e30f};
  float lrow[4] = {0.f, 0.f, 0.f, 0.f};

  for (int kt = 0; kt <= qt; kt++) {
    const int kv0 = kt * 64;
    __syncthreads();
    // stage K (swizzled source -> linear LDS; read applies same XOR)
#pragma unroll
    for (int i = 0; i < 4; i++) {
      int row = w * 16 + i * 4 + lg;
      int sb = (l15 * 16) ^ ((row & 7) << 4);
      const bf16* g = QKV + (size_t)(b * T_SEQ + kv0 + row) * NQKV + DMODEL + kvh * DHEAD + (sb >> 1);
      gload_lds16(g, Ks + (w * 4 + i) * 512);
    }
    // stage V transposed (reg -> scalar ds_write)
#pragma unroll
    for (int i = 0; i < 4; i++) {
      int kv = i * 16 + (tid >> 4);
      int d0 = (tid & 15) * 8;
      bf16x8 vv = *(const bf16x8*)(QKV + (size_t)(b * T_SEQ + kv0 + kv) * NQKV + 2560 + kvh * DHEAD + d0);
#pragma unroll
      for (int j = 0; j < 8; j++) Vt[d0 + j][kv] = vv[j];
    }
    __syncthreads();

    // S = (Q K^T) for this wave's 16 q-rows x 64 kv
    f32x4 s[4] = {};
#pragma unroll
    for (int kk = 0; kk < 4; kk++) {
#pragma unroll
      for (int n = 0; n < 4; n++) {
        int row = n * 16 + l15;
        int cb = (kk * 64 + lg * 16) ^ ((row & 7) << 4);
        bf16x8 kf = *(const bf16x8*)((const char*)Ks + row * 256 + cb);
        s[n] = __builtin_amdgcn_mfma_f32_16x16x32_bf16(qreg[kk], kf, s[n], 0, 0, 0);
      }
    }
    // scale + causal mask + row max
    float pm[4] = {-1e30f, -1e30f, -1e30f, -1e30f};
    const bool diag = (kt == qt);
#pragma unroll
    for (int n = 0; n < 4; n++)
#pragma unroll
      for (int i = 0; i < 4; i++) {
        float sv = s[n][i] * scale;
        if (diag && (kv0 + n * 16 + l15 > qt * 64 + w * 16 + lg * 4 + i)) sv = -1e30f;
        s[n][i] = sv;
        pm[i] = fmaxf(pm[i], sv);
      }
#pragma unroll
    for (int i = 0; i < 4; i++) {
      float v = pm[i];
      v = fmaxf(v, __shfl_xor(v, 1));
      v = fmaxf(v, __shfl_xor(v, 2));
      v = fmaxf(v, __shfl_xor(v, 4));
      v = fmaxf(v, __shfl_xor(v, 8));
      pm[i] = v;
    }
    float alpha[4];
#pragma unroll
    for (int i = 0; i < 4; i++) {
      float mn = fmaxf(mrow[i], pm[i]);
      alpha[i] = expf(mrow[i] - mn);
      mrow[i] = mn;
    }
    float rs[4] = {0.f, 0.f, 0.f, 0.f};
#pragma unroll
    for (int n = 0; n < 4; n++)
#pragma unroll
      for (int i = 0; i < 4; i++) {
        float p = expf(s[n][i] - mrow[i]);
        s[n][i] = p;
        rs[i] += p;
      }
#pragma unroll
    for (int i = 0; i < 4; i++) {
      float v = rs[i];
      v += __shfl_xor(v, 1);
      v += __shfl_xor(v, 2);
      v += __shfl_xor(v, 4);
      v += __shfl_xor(v, 8);
      lrow[i] = lrow[i] * alpha[i] + v;
    }
#pragma unroll
    for (int n = 0; n < 8; n++)
#pragma unroll
      for (int i = 0; i < 4; i++) o[n][i] *= alpha[i];
    // P -> LDS (bf16)
#pragma unroll
    for (int n = 0; n < 4; n++)
#pragma unroll
      for (int i = 0; i < 4; i++)
        Ps[w][lg * 4 + i][n * 16 + l15] = (bf16)s[n][i];
    // O += P V
#pragma unroll
    for (int kc = 0; kc < 2; kc++) {
      bf16x8 pa = *(const bf16x8*)(&Ps[w][l15][kc * 32 + lg * 8]);
#pragma unroll
      for (int n = 0; n < 8; n++) {
        bf16x8 vf = *(const bf16x8*)(&Vt[n * 16 + l15][kc * 32 + lg * 8]);
        o[n] = __builtin_amdgcn_mfma_f32_16x16x32_bf16(pa, vf, o[n], 0, 0, 0);
      }
    }
  }
  // epilogue: O /= l, store bf16 to AO[b*T+t][h*128+d]
  const size_t obase = (size_t)(b * T_SEQ + qt * 64 + w * 16 + lg * 4) * DMODEL + h * DHEAD + l15;
#pragma unroll
  for (int i = 0; i < 4; i++) {
    float inv = 1.0f / lrow[i];
#pragma unroll
    for (int n = 0; n < 8; n++)
      AO[obase + (size_t)i * DMODEL + n * 16] = (bf16)(o[n][i] * inv);
  }
}

extern "C" void kernel_launch(void* const* d_in, const int* in_sizes, int n_in,
                              void* d_out, int out_size, void* d_ws, size_t ws_size,
                              hipStream_t stream) {
  const float* x  = (const float*)d_in[0];
  const float* Wq = (const float*)d_in[1];
  const float* Wk = (const float*)d_in[2];
  const float* Wv = (const float*)d_in[3];
  const float* Wo = (const float*)d_in[4];
  char* ws = (char*)d_ws;
  bf16* xb  = (bf16*)ws;                                             // 4096x2048
  bf16* WT  = (bf16*)(ws + 16777216ull);                             // 3072x2048 (WqT|WkT|WvT)
  bf16* WoT = (bf16*)(ws + 16777216ull + 12582912ull);               // 2048x2048
  bf16* QKV = (bf16*)(ws + 16777216ull + 12582912ull + 8388608ull);  // 4096x3072
  bf16* AO  = (bf16*)(ws + 16777216ull + 12582912ull + 8388608ull + 25165824ull); // 4096x2048
  float* out = (float*)d_out;

  k_cvt<<<8192, 256, 0, stream>>>(x, xb);
  k_twt<<<dim3(32, 32), 256, 0, stream>>>(Wq, WT, 2048, 2048);
  k_twt<<<dim3(32, 8), 256, 0, stream>>>(Wk, WT + (size_t)2048 * 2048, 2048, 512);
  k_twt<<<dim3(32, 8), 256, 0, stream>>>(Wv, WT + (size_t)2560 * 2048, 2048, 512);
  k_twt<<<dim3(32, 32), 256, 0, stream>>>(Wo, WoT, 2048, 2048);
  k_gemm<false><<<dim3(32, 24), 256, 0, stream>>>(xb, WT, QKV, 4096, 3072, 2048);
  k_rope<<<5120, 256, 0, stream>>>(QKV);
  k_flash<<<dim3(32, 32), 256, 0, stream>>>(QKV, AO);
  k_gemm<true><<<dim3(32, 16), 256, 0, stream>>>(AO, WoT, out, 4096, 2048, 2048);
}

// Round 2
// 544.427 us; speedup vs baseline: 1.0835x; 1.0835x over previous
//
#include <hip/hip_runtime.h>
#include <stdint.h>

typedef __bf16 bf16;
typedef __bf16 bf16x8 __attribute__((ext_vector_type(8)));
typedef __bf16 bf16x4 __attribute__((ext_vector_type(4)));
typedef float  f32x4  __attribute__((ext_vector_type(4)));

#define T_SEQ  2048
#define NHEAD  16
#define DHEAD  128
#define DMODEL 2048
#define NQKV   3072   // 2048 Q | 512 K | 512 V per row

__device__ __forceinline__ void gload_lds16(const void* g, void* l) {
  __builtin_amdgcn_global_load_lds(
      (const __attribute__((address_space(1))) uint32_t*)g,
      (__attribute__((address_space(3))) uint32_t*)l, 16, 0, 0);
}

// ---------------- fp32 -> bf16 cast (x) ----------------
__global__ void k_cvt(const float* __restrict__ in, bf16* __restrict__ out) {
  int i = (blockIdx.x * 256 + threadIdx.x) * 4;
  float4 v = *(const float4*)(in + i);
  bf16x4 o = { (bf16)v.x, (bf16)v.y, (bf16)v.z, (bf16)v.w };
  *(bf16x4*)(out + i) = o;
}

// ---------------- W (K x N fp32) -> WT (N x K bf16) ----------------
__global__ __launch_bounds__(256) void k_twt(const float* __restrict__ W,
                                             bf16* __restrict__ WT, int K, int N) {
  __shared__ float t[64][65];
  int k0 = blockIdx.x * 64, n0 = blockIdx.y * 64;
  int r4 = threadIdx.x >> 6, c = threadIdx.x & 63;
#pragma unroll
  for (int i = 0; i < 16; i++) {
    int r = i * 4 + r4;
    t[r][c] = W[(size_t)(k0 + r) * N + n0 + c];
  }
  __syncthreads();
#pragma unroll
  for (int i = 0; i < 16; i++) {
    int r = i * 4 + r4;
    WT[(size_t)(n0 + r) * K + k0 + c] = (bf16)t[c][r];
  }
}

// ---------------- GEMM: C[M,N] = A[M,K] * BT[N,K]^T  (m97 structure) ----------------
template<bool F32OUT>
__global__ __launch_bounds__(256) void k_gemm(const bf16* __restrict__ A,
                                              const bf16* __restrict__ BT,
                                              void* __restrict__ C,
                                              int M, int N, int K) {
  __shared__ __align__(16) bf16 As[128 * 64];
  __shared__ __align__(16) bf16 Bs[128 * 64];
  const int m0 = blockIdx.x * 128, n0 = blockIdx.y * 128;
  const int tid = threadIdx.x;
  const int lane = tid & 63, w = tid >> 6;
  const int wr = w >> 1, wc = w & 1;
  const int l15 = lane & 15, lg = lane >> 4;
  f32x4 acc[4][4] = {};

  const int rA = w * 32 + (lane >> 3);
  const int cA = (lane & 7) * 8;
  const bf16* gA = A  + (size_t)(m0 + rA) * K + cA;
  const bf16* gB = BT + (size_t)(n0 + rA) * K + cA;

  for (int k0 = 0; k0 < K; k0 += 64) {
    __syncthreads();
#pragma unroll
    for (int i = 0; i < 4; i++) {
      gload_lds16(gA + (size_t)i * 8 * K + k0, As + (w * 4 + i) * 512);
      gload_lds16(gB + (size_t)i * 8 * K + k0, Bs + (w * 4 + i) * 512);
    }
    __syncthreads();
#pragma unroll
    for (int kk = 0; kk < 2; kk++) {
      bf16x8 af[4], bfr[4];
#pragma unroll
      for (int m = 0; m < 4; m++)
        af[m] = *(const bf16x8*)(As + (wr * 64 + m * 16 + l15) * 64 + kk * 32 + lg * 8);
#pragma unroll
      for (int n = 0; n < 4; n++)
        bfr[n] = *(const bf16x8*)(Bs + (wc * 64 + n * 16 + l15) * 64 + kk * 32 + lg * 8);
#pragma unroll
      for (int m = 0; m < 4; m++)
#pragma unroll
        for (int n = 0; n < 4; n++)
          acc[m][n] = __builtin_amdgcn_mfma_f32_16x16x32_bf16(af[m], bfr[n], acc[m][n], 0, 0, 0);
    }
  }
  const int r0 = m0 + wr * 64 + lg * 4;
  const int c0 = n0 + wc * 64 + l15;
#pragma unroll
  for (int m = 0; m < 4; m++)
#pragma unroll
    for (int n = 0; n < 4; n++)
#pragma unroll
      for (int i = 0; i < 4; i++) {
        size_t idx = (size_t)(r0 + m * 16 + i) * N + (c0 + n * 16);
        if (F32OUT) ((float*)C)[idx] = acc[m][n][i];
        else        ((bf16*)C)[idx]  = (bf16)acc[m][n][i];
      }
}

// ---------------- in-place RoPE on QKV cols [0,2560) ----------------
__global__ void k_rope(bf16* __restrict__ QKV) {
  const float L2B = 0.20762050593046007f;  // log2(10000)/64
  int tid = blockIdx.x * 256 + threadIdx.x;
  int row = tid / 320;
  int c8 = (tid - row * 320) * 8;
  int t = row & (T_SEQ - 1);
  bf16* p = QKV + (size_t)row * NQKV + c8;
  bf16x8 v = *(const bf16x8*)p;
  int ib = (c8 & 127) >> 1;
  bf16x8 o;
#pragma unroll
  for (int m = 0; m < 4; m++) {
    float inv = exp2f(-(float)(ib + m) * L2B);
    float ang = (float)t * inv;
    float cs, sn;
    __sincosf(ang, &sn, &cs);
    float x1 = (float)v[2 * m], x2 = (float)v[2 * m + 1];
    o[2 * m]     = (bf16)(x1 * cs - x2 * sn);
    o[2 * m + 1] = (bf16)(x1 * sn + x2 * cs);
  }
  *(bf16x8*)p = o;
}

// ---------------- flash attention (causal, GQA), paired q-tiles, 2-phase pipeline ----
__global__ __launch_bounds__(256, 2) void k_flash(const bf16* __restrict__ QKV,
                                                  bf16* __restrict__ AO) {
  __shared__ __align__(16) bf16 Ks[2][64 * 128];   // row*256B, 16B-chunk XOR (row&7)
  __shared__ __align__(16) char Vt[2][128 * 128];  // Vt[d][kv]: d*128B, chunk XOR (d>>1)&7
  __shared__ __align__(16) bf16 Ps[4][16][72];
  const int p  = blockIdx.x;             // 0..15 -> q-tiles p and 31-p
  const int bh = blockIdx.y;
  const int b = bh >> 4, h = bh & 15, kvh = h >> 2;
  const int qtA = p, qtB = 31 - p;
  const int tid = threadIdx.x, lane = tid & 63, w = tid >> 6;
  const int l15 = lane & 15, lg = lane >> 4;
  const float scale = 0.08838834764831845f;

  // Q fragments for both q-tiles (A-operand: q = lane&15, k = kk*32+lg*8+j)
  bf16x8 qA[4], qB[4];
  {
    const size_t qoA = (size_t)(b * T_SEQ + qtA * 64 + w * 16 + l15) * NQKV + h * DHEAD;
    const size_t qoB = (size_t)(b * T_SEQ + qtB * 64 + w * 16 + l15) * NQKV + h * DHEAD;
#pragma unroll
    for (int kk = 0; kk < 4; kk++) {
      qA[kk] = *(const bf16x8*)(QKV + qoA + kk * 32 + lg * 8);
      qB[kk] = *(const bf16x8*)(QKV + qoB + kk * 32 + lg * 8);
    }
  }
  f32x4 oA[8] = {}, oB[8] = {};
  float mA[4], lA[4], mB[4], lB[4];
#pragma unroll
  for (int i = 0; i < 4; i++) { mA[i] = mB[i] = -1e30f; lA[i] = lB[i] = 0.f; }

  // V staging geometry: thread covers d2,d2+1 x 16 kv (coalesced 4B global loads)
  const int d2 = (tid & 63) * 2;
  const int kvg = tid >> 6;
  const int swzV = (d2 >> 1) & 7;
  uint32_t vreg[16];

  const bf16* Kbase = QKV + (size_t)b * T_SEQ * NQKV + DMODEL + kvh * DHEAD;
  const bf16* Vbase = QKV + (size_t)b * T_SEQ * NQKV + 2560 + kvh * DHEAD;

  auto issueK = [&](int buf, int kt) {
#pragma unroll
    for (int i = 0; i < 4; i++) {
      int row = w * 16 + i * 4 + lg;
      int sb = (l15 * 16) ^ ((row & 7) << 4);
      gload_lds16(Kbase + (size_t)(kt * 64 + row) * NQKV + (sb >> 1),
                  (bf16*)Ks[buf] + (w * 4 + i) * 512);
    }
  };
  auto loadV = [&](int kt) {
    const bf16* src = Vbase + (size_t)(kt * 64 + kvg * 16) * NQKV + d2;
#pragma unroll
    for (int j = 0; j < 16; j++)
      vreg[j] = *(const uint32_t*)(src + (size_t)j * NQKV);
  };
  auto writeV = [&](int buf) {
    char* vt = Vt[buf];
    const int c0 = kvg * 2;
    uint32_t a0[4], a1[4], b0[4], b1[4];
#pragma unroll
    for (int j = 0; j < 4; j++) {
      a0[j] = (vreg[2*j]     & 0xffffu) | (vreg[2*j+1]     << 16);
      a1[j] = (vreg[8+2*j]   & 0xffffu) | (vreg[8+2*j+1]   << 16);
      b0[j] = (vreg[2*j]     >> 16)     | (vreg[2*j+1]     & 0xffff0000u);
      b1[j] = (vreg[8+2*j]   >> 16)     | (vreg[8+2*j+1]   & 0xffff0000u);
    }
    uint4 t0; t0.x = a0[0]; t0.y = a0[1]; t0.z = a0[2]; t0.w = a0[3];
    uint4 t1; t1.x = a1[0]; t1.y = a1[1]; t1.z = a1[2]; t1.w = a1[3];
    uint4 t2; t2.x = b0[0]; t2.y = b0[1]; t2.z = b0[2]; t2.w = b0[3];
    uint4 t3; t3.x = b1[0]; t3.y = b1[1]; t3.z = b1[2]; t3.w = b1[3];
    *(uint4*)(vt + d2 * 128       + (((c0    ) ^ swzV) << 4)) = t0;
    *(uint4*)(vt + d2 * 128       + (((c0 + 1) ^ swzV) << 4)) = t1;
    *(uint4*)(vt + (d2 + 1) * 128 + (((c0    ) ^ swzV) << 4)) = t2;
    *(uint4*)(vt + (d2 + 1) * 128 + (((c0 + 1) ^ swzV) << 4)) = t3;
  };

  auto compute = [&](int buf, int kt, const bf16x8* qreg, f32x4* o,
                     float* mrow, float* lrow, int qt_this) {
    const int kv0 = kt * 64;
    f32x4 s[4] = {};
    const char* ks = (const char*)Ks[buf];
#pragma unroll
    for (int kk = 0; kk < 4; kk++)
#pragma unroll
      for (int n = 0; n < 4; n++) {
        int row = n * 16 + l15;
        int cb = (kk * 64 + lg * 16) ^ ((row & 7) << 4);
        bf16x8 kf = *(const bf16x8*)(ks + row * 256 + cb);
        s[n] = __builtin_amdgcn_mfma_f32_16x16x32_bf16(qreg[kk], kf, s[n], 0, 0, 0);
      }
    const bool diag = (kt == qt_this);
    float pm[4] = {-1e30f, -1e30f, -1e30f, -1e30f};
#pragma unroll
    for (int n = 0; n < 4; n++)
#pragma unroll
      for (int i = 0; i < 4; i++) {
        float sv = s[n][i] * scale;
        if (diag && (kv0 + n * 16 + l15 > qt_this * 64 + w * 16 + lg * 4 + i)) sv = -1e30f;
        s[n][i] = sv;
        pm[i] = fmaxf(pm[i], sv);
      }
#pragma unroll
    for (int i = 0; i < 4; i++) {
      float v = pm[i];
      v = fmaxf(v, __shfl_xor(v, 1));
      v = fmaxf(v, __shfl_xor(v, 2));
      v = fmaxf(v, __shfl_xor(v, 4));
      v = fmaxf(v, __shfl_xor(v, 8));
      pm[i] = v;
    }
    float alpha[4];
#pragma unroll
    for (int i = 0; i < 4; i++) {
      float mn = fmaxf(mrow[i], pm[i]);
      alpha[i] = __expf(mrow[i] - mn);
      mrow[i] = mn;
    }
    float rs[4] = {0.f, 0.f, 0.f, 0.f};
#pragma unroll
    for (int n = 0; n < 4; n++)
#pragma unroll
      for (int i = 0; i < 4; i++) {
        float pv = __expf(s[n][i] - mrow[i]);
        s[n][i] = pv;
        rs[i] += pv;
      }
#pragma unroll
    for (int i = 0; i < 4; i++) {
      float v = rs[i];
      v += __shfl_xor(v, 1);
      v += __shfl_xor(v, 2);
      v += __shfl_xor(v, 4);
      v += __shfl_xor(v, 8);
      lrow[i] = lrow[i] * alpha[i] + v;
    }
#pragma unroll
    for (int n = 0; n < 8; n++)
#pragma unroll
      for (int i = 0; i < 4; i++) o[n][i] *= alpha[i];
#pragma unroll
    for (int n = 0; n < 4; n++)
#pragma unroll
      for (int i = 0; i < 4; i++)
        Ps[w][lg * 4 + i][n * 16 + l15] = (bf16)s[n][i];
    const char* vt = (const char*)Vt[buf];
#pragma unroll
    for (int kc = 0; kc < 2; kc++) {
      bf16x8 pa = *(const bf16x8*)(&Ps[w][l15][kc * 32 + lg * 8]);
#pragma unroll
      for (int n = 0; n < 8; n++) {
        int d = n * 16 + l15;
        bf16x8 vf = *(const bf16x8*)(vt + d * 128 + ((((kc << 2) + lg) ^ ((d >> 1) & 7)) << 4));
        o[n] = __builtin_amdgcn_mfma_f32_16x16x32_bf16(pa, vf, o[n], 0, 0, 0);
      }
    }
  };

  const int NT = qtB + 1;
  // prologue: stage tile 0
  issueK(0, 0);
  loadV(0);
  writeV(0);
  __syncthreads();

  for (int kt = 0; kt < NT; kt++) {
    const int cur = kt & 1, nxt = cur ^ 1;
    const bool pf = (kt + 1 < NT);
    if (pf) { issueK(nxt, kt + 1); loadV(kt + 1); }
    compute(cur, kt, qB, oB, mB, lB, qtB);
    if (kt <= qtA) compute(cur, kt, qA, oA, mA, lA, qtA);
    if (pf) writeV(nxt);
    __syncthreads();
  }

  auto store = [&](const f32x4* o, const float* lrow, int qt_this) {
    const size_t obase = (size_t)(b * T_SEQ + qt_this * 64 + w * 16 + lg * 4) * DMODEL + h * DHEAD + l15;
#pragma unroll
    for (int i = 0; i < 4; i++) {
      float inv = 1.0f / lrow[i];
#pragma unroll
      for (int n = 0; n < 8; n++)
        AO[obase + (size_t)i * DMODEL + n * 16] = (bf16)(o[n][i] * inv);
    }
  };
  store(oA, lA, qtA);
  store(oB, lB, qtB);
}

extern "C" void kernel_launch(void* const* d_in, const int* in_sizes, int n_in,
                              void* d_out, int out_size, void* d_ws, size_t ws_size,
                              hipStream_t stream) {
  const float* x  = (const float*)d_in[0];
  const float* Wq = (const float*)d_in[1];
  const float* Wk = (const float*)d_in[2];
  const float* Wv = (const float*)d_in[3];
  const float* Wo = (const float*)d_in[4];
  char* ws = (char*)d_ws;
  bf16* xb  = (bf16*)ws;                                             // 4096x2048
  bf16* WT  = (bf16*)(ws + 16777216ull);                             // 3072x2048 (WqT|WkT|WvT)
  bf16* WoT = (bf16*)(ws + 16777216ull + 12582912ull);               // 2048x2048
  bf16* QKV = (bf16*)(ws + 16777216ull + 12582912ull + 8388608ull);  // 4096x3072
  bf16* AO  = (bf16*)(ws + 16777216ull + 12582912ull + 8388608ull + 25165824ull); // 4096x2048
  float* out = (float*)d_out;

  k_cvt<<<8192, 256, 0, stream>>>(x, xb);
  k_twt<<<dim3(32, 32), 256, 0, stream>>>(Wq, WT, 2048, 2048);
  k_twt<<<dim3(32, 8), 256, 0, stream>>>(Wk, WT + (size_t)2048 * 2048, 2048, 512);
  k_twt<<<dim3(32, 8), 256, 0, stream>>>(Wv, WT + (size_t)2560 * 2048, 2048, 512);
  k_twt<<<dim3(32, 32), 256, 0, stream>>>(Wo, WoT, 2048, 2048);
  k_gemm<false><<<dim3(32, 24), 256, 0, stream>>>(xb, WT, QKV, 4096, 3072, 2048);
  k_rope<<<5120, 256, 0, stream>>>(QKV);
  k_flash<<<dim3(16, 32), 256, 0, stream>>>(QKV, AO);
  k_gemm<true><<<dim3(32, 16), 256, 0, stream>>>(AO, WoT, out, 4096, 2048, 2048);
}

// Round 3
// 319.790 us; speedup vs baseline: 1.8446x; 1.7025x over previous
//
#include <hip/hip_runtime.h>
#include <stdint.h>

typedef __bf16 bf16;
typedef __bf16 bf16x8 __attribute__((ext_vector_type(8)));
typedef __bf16 bf16x4 __attribute__((ext_vector_type(4)));
typedef float  f32x4  __attribute__((ext_vector_type(4)));

#define T_SEQ  2048
#define NHEAD  16
#define DHEAD  128
#define DMODEL 2048
#define NQKV   3072   // 2048 Q | 512 K | 512 V per row
#define UNROLL _Pragma("unroll")

__device__ __forceinline__ void gload_lds16(const void* g, void* l) {
  __builtin_amdgcn_global_load_lds(
      (const __attribute__((address_space(1))) uint32_t*)g,
      (__attribute__((address_space(3))) uint32_t*)l, 16, 0, 0);
}

// ---------------- fp32 -> bf16 cast (x) ----------------
__global__ void k_cvt(const float* __restrict__ in, bf16* __restrict__ out) {
  int i = (blockIdx.x * 256 + threadIdx.x) * 4;
  float4 v = *(const float4*)(in + i);
  bf16x4 o = { (bf16)v.x, (bf16)v.y, (bf16)v.z, (bf16)v.w };
  *(bf16x4*)(out + i) = o;
}

// ---------------- W (K x N fp32) -> WT (N x K bf16) ----------------
__global__ __launch_bounds__(256) void k_twt(const float* __restrict__ W,
                                             bf16* __restrict__ WT, int K, int N) {
  __shared__ float t[64][65];
  int k0 = blockIdx.x * 64, n0 = blockIdx.y * 64;
  int r4 = threadIdx.x >> 6, c = threadIdx.x & 63;
#pragma unroll
  for (int i = 0; i < 16; i++) {
    int r = i * 4 + r4;
    t[r][c] = W[(size_t)(k0 + r) * N + n0 + c];
  }
  __syncthreads();
#pragma unroll
  for (int i = 0; i < 16; i++) {
    int r = i * 4 + r4;
    WT[(size_t)(n0 + r) * K + k0 + c] = (bf16)t[c][r];
  }
}

// ---------------- V pre-transpose: QKV V-cols -> Vtg[(b*4+kvh)*128 + d][t] ----
__global__ __launch_bounds__(256) void k_vt(const bf16* __restrict__ QKV,
                                            bf16* __restrict__ Vtg) {
  __shared__ bf16 t[64][65];
  const int t0 = blockIdx.x * 64, d0 = blockIdx.y * 64;
  const int g = blockIdx.z, b = g >> 2, kvh = g & 3;
  const bf16* src = QKV + (size_t)b * T_SEQ * NQKV + 2560 + kvh * DHEAD;
  bf16* dst = Vtg + ((size_t)(b * 4 + kvh) * 128 + d0) * T_SEQ + t0;
  const int r4 = threadIdx.x >> 6, c = threadIdx.x & 63;
#pragma unroll
  for (int i = 0; i < 16; i++) {
    int r = i * 4 + r4;
    t[r][c] = src[(size_t)(t0 + r) * NQKV + d0 + c];
  }
  __syncthreads();
#pragma unroll
  for (int i = 0; i < 16; i++) {
    int r = i * 4 + r4;
    dst[(size_t)r * T_SEQ + c] = t[c][r];
  }
}

// ---------------- GEMM: C[M,N] = A[M,K] * BT[N,K]^T  (m97 structure) ----------------
template<bool F32OUT>
__global__ __launch_bounds__(256) void k_gemm(const bf16* __restrict__ A,
                                              const bf16* __restrict__ BT,
                                              void* __restrict__ C,
                                              int M, int N, int K) {
  __shared__ __align__(16) bf16 As[128 * 64];
  __shared__ __align__(16) bf16 Bs[128 * 64];
  const int m0 = blockIdx.x * 128, n0 = blockIdx.y * 128;
  const int tid = threadIdx.x;
  const int lane = tid & 63, w = tid >> 6;
  const int wr = w >> 1, wc = w & 1;
  const int l15 = lane & 15, lg = lane >> 4;
  f32x4 acc[4][4] = {};

  const int rA = w * 32 + (lane >> 3);
  const int cA = (lane & 7) * 8;
  const bf16* gA = A  + (size_t)(m0 + rA) * K + cA;
  const bf16* gB = BT + (size_t)(n0 + rA) * K + cA;

  for (int k0 = 0; k0 < K; k0 += 64) {
    __syncthreads();
#pragma unroll
    for (int i = 0; i < 4; i++) {
      gload_lds16(gA + (size_t)i * 8 * K + k0, As + (w * 4 + i) * 512);
      gload_lds16(gB + (size_t)i * 8 * K + k0, Bs + (w * 4 + i) * 512);
    }
    __syncthreads();
#pragma unroll
    for (int kk = 0; kk < 2; kk++) {
      bf16x8 af[4], bfr[4];
#pragma unroll
      for (int m = 0; m < 4; m++)
        af[m] = *(const bf16x8*)(As + (wr * 64 + m * 16 + l15) * 64 + kk * 32 + lg * 8);
#pragma unroll
      for (int n = 0; n < 4; n++)
        bfr[n] = *(const bf16x8*)(Bs + (wc * 64 + n * 16 + l15) * 64 + kk * 32 + lg * 8);
#pragma unroll
      for (int m = 0; m < 4; m++)
#pragma unroll
        for (int n = 0; n < 4; n++)
          acc[m][n] = __builtin_amdgcn_mfma_f32_16x16x32_bf16(af[m], bfr[n], acc[m][n], 0, 0, 0);
    }
  }
  const int r0 = m0 + wr * 64 + lg * 4;
  const int c0 = n0 + wc * 64 + l15;
#pragma unroll
  for (int m = 0; m < 4; m++)
#pragma unroll
    for (int n = 0; n < 4; n++)
#pragma unroll
      for (int i = 0; i < 4; i++) {
        size_t idx = (size_t)(r0 + m * 16 + i) * N + (c0 + n * 16);
        if (F32OUT) ((float*)C)[idx] = acc[m][n][i];
        else        ((bf16*)C)[idx]  = (bf16)acc[m][n][i];
      }
}

// ---------------- in-place RoPE on QKV cols [0,2560) ----------------
__global__ void k_rope(bf16* __restrict__ QKV) {
  const float L2B = 0.20762050593046007f;  // log2(10000)/64
  int tid = blockIdx.x * 256 + threadIdx.x;
  int row = tid / 320;
  int c8 = (tid - row * 320) * 8;
  int t = row & (T_SEQ - 1);
  bf16* p = QKV + (size_t)row * NQKV + c8;
  bf16x8 v = *(const bf16x8*)p;
  int ib = (c8 & 127) >> 1;
  bf16x8 o;
#pragma unroll
  for (int m = 0; m < 4; m++) {
    float inv = exp2f(-(float)(ib + m) * L2B);
    float ang = (float)t * inv;
    float cs, sn;
    __sincosf(ang, &sn, &cs);
    float x1 = (float)v[2 * m], x2 = (float)v[2 * m + 1];
    o[2 * m]     = (bf16)(x1 * cs - x2 * sn);
    o[2 * m + 1] = (bf16)(x1 * sn + x2 * cs);
  }
  *(bf16x8*)p = o;
}

// ---------------- flash attention (causal, GQA), paired q-tiles ----------------
// Per-tile compute on NAMED register arrays (macro: no pointer-passing => no scratch).
#define COMPUTE(qreg, o, mrow, lrow, qt_this, kt, cur) do {                               \
    const int kv0_ = (kt) * 64;                                                           \
    f32x4 s_[4] = {};                                                                     \
    const char* ks_ = (const char*)Ks[cur];                                               \
    UNROLL for (int kk = 0; kk < 4; kk++)                                                 \
      UNROLL for (int n = 0; n < 4; n++) {                                                \
        int row_ = n * 16 + l15;                                                          \
        int cb_ = (kk * 64 + lg * 16) ^ ((row_ & 7) << 4);                                \
        bf16x8 kf_ = *(const bf16x8*)(ks_ + row_ * 256 + cb_);                            \
        s_[n] = __builtin_amdgcn_mfma_f32_16x16x32_bf16(qreg[kk], kf_, s_[n], 0, 0, 0);   \
      }                                                                                   \
    const bool diag_ = ((kt) == (qt_this));                                               \
    float pm_[4] = {-1e30f, -1e30f, -1e30f, -1e30f};                                      \
    UNROLL for (int n = 0; n < 4; n++)                                                    \
      UNROLL for (int i = 0; i < 4; i++) {                                                \
        float sv_ = s_[n][i] * scale;                                                     \
        if (diag_ && (kv0_ + n * 16 + l15 > (qt_this) * 64 + w * 16 + lg * 4 + i))        \
          sv_ = -1e30f;                                                                   \
        s_[n][i] = sv_;                                                                   \
        pm_[i] = fmaxf(pm_[i], sv_);                                                      \
      }                                                                                   \
    UNROLL for (int i = 0; i < 4; i++) {                                                  \
      float v_ = pm_[i];                                                                  \
      v_ = fmaxf(v_, __shfl_xor(v_, 1));                                                  \
      v_ = fmaxf(v_, __shfl_xor(v_, 2));                                                  \
      v_ = fmaxf(v_, __shfl_xor(v_, 4));                                                  \
      v_ = fmaxf(v_, __shfl_xor(v_, 8));                                                  \
      pm_[i] = v_;                                                                        \
    }                                                                                     \
    float al_[4];                                                                         \
    UNROLL for (int i = 0; i < 4; i++) {                                                  \
      float mn_ = fmaxf(mrow[i], pm_[i]);                                                 \
      al_[i] = __expf(mrow[i] - mn_);                                                     \
      mrow[i] = mn_;                                                                      \
    }                                                                                     \
    float rs_[4] = {0.f, 0.f, 0.f, 0.f};                                                  \
    UNROLL for (int n = 0; n < 4; n++)                                                    \
      UNROLL for (int i = 0; i < 4; i++) {                                                \
        float pv_ = __expf(s_[n][i] - mrow[i]);                                           \
        s_[n][i] = pv_;                                                                   \
        rs_[i] += pv_;                                                                    \
      }                                                                                   \
    UNROLL for (int i = 0; i < 4; i++) {                                                  \
      float v_ = rs_[i];                                                                  \
      v_ += __shfl_xor(v_, 1);                                                            \
      v_ += __shfl_xor(v_, 2);                                                            \
      v_ += __shfl_xor(v_, 4);                                                            \
      v_ += __shfl_xor(v_, 8);                                                            \
      lrow[i] = lrow[i] * al_[i] + v_;                                                    \
    }                                                                                     \
    UNROLL for (int n = 0; n < 8; n++)                                                    \
      UNROLL for (int i = 0; i < 4; i++) o[n][i] *= al_[i];                               \
    UNROLL for (int n = 0; n < 4; n++)                                                    \
      UNROLL for (int i = 0; i < 4; i++)                                                  \
        Ps[w][lg * 4 + i][n * 16 + l15] = (bf16)s_[n][i];                                 \
    const char* vs_ = (const char*)Vs[cur];                                               \
    UNROLL for (int kc = 0; kc < 2; kc++) {                                               \
      bf16x8 pa_ = *(const bf16x8*)(&Ps[w][l15][kc * 32 + lg * 8]);                       \
      UNROLL for (int n = 0; n < 8; n++) {                                                \
        int d_ = n * 16 + l15;                                                            \
        bf16x8 vf_ = *(const bf16x8*)(vs_ + d_ * 128 + ((((kc << 2) + lg) ^ (d_ & 7)) << 4)); \
        o[n] = __builtin_amdgcn_mfma_f32_16x16x32_bf16(pa_, vf_, o[n], 0, 0, 0);          \
      }                                                                                   \
    }                                                                                     \
  } while (0)

__global__ __launch_bounds__(256) void k_flash(const bf16* __restrict__ QKV,
                                               const bf16* __restrict__ Vtg,
                                               bf16* __restrict__ AO) {
  __shared__ __align__(16) bf16 Ks[2][64 * 128];   // [kv row]*256B, chunk XOR (row&7)
  __shared__ __align__(16) bf16 Vs[2][128 * 64];   // [d row]*128B,  chunk XOR (d&7)
  __shared__ __align__(16) bf16 Ps[4][16][72];
  const int p  = blockIdx.x;             // 0..15 -> q-tiles p and 31-p
  const int bh = blockIdx.y;
  const int b = bh >> 4, h = bh & 15, kvh = h >> 2;
  const int qtA = p, qtB = 31 - p;
  const int tid = threadIdx.x, lane = tid & 63, w = tid >> 6;
  const int l15 = lane & 15, lg = lane >> 4;
  const float scale = 0.08838834764831845f;

  bf16x8 qA[4], qB[4];
  {
    const size_t qoA = (size_t)(b * T_SEQ + qtA * 64 + w * 16 + l15) * NQKV + h * DHEAD;
    const size_t qoB = (size_t)(b * T_SEQ + qtB * 64 + w * 16 + l15) * NQKV + h * DHEAD;
    UNROLL for (int kk = 0; kk < 4; kk++) {
      qA[kk] = *(const bf16x8*)(QKV + qoA + kk * 32 + lg * 8);
      qB[kk] = *(const bf16x8*)(QKV + qoB + kk * 32 + lg * 8);
    }
  }
  f32x4 oA[8] = {}, oB[8] = {};
  float mA[4], lAc[4], mB[4], lBc[4];
  UNROLL for (int i = 0; i < 4; i++) { mA[i] = mB[i] = -1e30f; lAc[i] = lBc[i] = 0.f; }

  const bf16* Kbase = QKV + (size_t)b * T_SEQ * NQKV + DMODEL + kvh * DHEAD;
  const bf16* Vbase = Vtg + (size_t)(b * 4 + kvh) * 128 * T_SEQ;

  auto issueK = [&](int buf, int kt) {
    UNROLL for (int i = 0; i < 4; i++) {
      int row = w * 16 + i * 4 + lg;
      int col = (l15 ^ (row & 7)) * 8;
      gload_lds16(Kbase + (size_t)(kt * 64 + row) * NQKV + col,
                  Ks[buf] + (w * 4 + i) * 512);
    }
  };
  auto issueV = [&](int buf, int kt) {
    UNROLL for (int i = 0; i < 4; i++) {
      int d = (w * 4 + i) * 8 + (lane >> 3);
      int u = lane & 7;
      gload_lds16(Vbase + (size_t)d * T_SEQ + kt * 64 + ((u ^ (d & 7)) * 8),
                  Vs[buf] + (w * 4 + i) * 512);
    }
  };

  issueK(0, 0);
  issueV(0, 0);
  __syncthreads();

  const int NT = qtB + 1;
  for (int kt = 0; kt < NT; kt++) {
    const int cur = kt & 1, nxt = cur ^ 1;
    if (kt + 1 < NT) { issueK(nxt, kt + 1); issueV(nxt, kt + 1); }
    COMPUTE(qB, oB, mB, lBc, qtB, kt, cur);
    if (kt <= qtA) COMPUTE(qA, oA, mA, lAc, qtA, kt, cur);
    __syncthreads();
  }

  {
    const size_t obase = (size_t)(b * T_SEQ + qtA * 64 + w * 16 + lg * 4) * DMODEL + h * DHEAD + l15;
    UNROLL for (int i = 0; i < 4; i++) {
      float inv = 1.0f / lAc[i];
      UNROLL for (int n = 0; n < 8; n++)
        AO[obase + (size_t)i * DMODEL + n * 16] = (bf16)(oA[n][i] * inv);
    }
  }
  {
    const size_t obase = (size_t)(b * T_SEQ + qtB * 64 + w * 16 + lg * 4) * DMODEL + h * DHEAD + l15;
    UNROLL for (int i = 0; i < 4; i++) {
      float inv = 1.0f / lBc[i];
      UNROLL for (int n = 0; n < 8; n++)
        AO[obase + (size_t)i * DMODEL + n * 16] = (bf16)(oB[n][i] * inv);
    }
  }
}

extern "C" void kernel_launch(void* const* d_in, const int* in_sizes, int n_in,
                              void* d_out, int out_size, void* d_ws, size_t ws_size,
                              hipStream_t stream) {
  const float* x  = (const float*)d_in[0];
  const float* Wq = (const float*)d_in[1];
  const float* Wk = (const float*)d_in[2];
  const float* Wv = (const float*)d_in[3];
  const float* Wo = (const float*)d_in[4];
  char* ws = (char*)d_ws;
  bf16* xb  = (bf16*)ws;                                             // 4096x2048
  bf16* WT  = (bf16*)(ws + 16777216ull);                             // 3072x2048 (WqT|WkT|WvT)
  bf16* WoT = (bf16*)(ws + 16777216ull + 12582912ull);               // 2048x2048
  bf16* QKV = (bf16*)(ws + 16777216ull + 12582912ull + 8388608ull);  // 4096x3072
  bf16* AO  = (bf16*)(ws + 16777216ull + 12582912ull + 8388608ull + 25165824ull); // 4096x2048
  bf16* Vtg = WT;   // WT is dead after the QKV GEMM; reuse first 4 MB for V^T
  float* out = (float*)d_out;

  k_cvt<<<8192, 256, 0, stream>>>(x, xb);
  k_twt<<<dim3(32, 32), 256, 0, stream>>>(Wq, WT, 2048, 2048);
  k_twt<<<dim3(32, 8), 256, 0, stream>>>(Wk, WT + (size_t)2048 * 2048, 2048, 512);
  k_twt<<<dim3(32, 8), 256, 0, stream>>>(Wv, WT + (size_t)2560 * 2048, 2048, 512);
  k_twt<<<dim3(32, 32), 256, 0, stream>>>(Wo, WoT, 2048, 2048);
  k_gemm<false><<<dim3(32, 24), 256, 0, stream>>>(xb, WT, QKV, 4096, 3072, 2048);
  k_rope<<<5120, 256, 0, stream>>>(QKV);
  k_vt<<<dim3(32, 2, 8), 256, 0, stream>>>(QKV, Vtg);
  k_flash<<<dim3(16, 32), 256, 0, stream>>>(QKV, Vtg, AO);
  k_gemm<true><<<dim3(32, 16), 256, 0, stream>>>(AO, WoT, out, 4096, 2048, 2048);
}

// Round 4
// 316.802 us; speedup vs baseline: 1.8620x; 1.0094x over previous
//
#include <hip/hip_runtime.h>
#include <stdint.h>

typedef __bf16 bf16;
typedef __bf16 bf16x8 __attribute__((ext_vector_type(8)));
typedef __bf16 bf16x4 __attribute__((ext_vector_type(4)));
typedef float  f32x4  __attribute__((ext_vector_type(4)));

#define T_SEQ  2048
#define NHEAD  16
#define DHEAD  128
#define DMODEL 2048
#define NQKV   3072   // 2048 Q | 512 K | 512 V per row
#define UNROLL _Pragma("unroll")

__device__ __forceinline__ void gload_lds16(const void* g, void* l) {
  __builtin_amdgcn_global_load_lds(
      (const __attribute__((address_space(1))) uint32_t*)g,
      (__attribute__((address_space(3))) uint32_t*)l, 16, 0, 0);
}

// ---------------- fp32 -> bf16 cast (x) ----------------
__global__ void k_cvt(const float* __restrict__ in, bf16* __restrict__ out) {
  int i = (blockIdx.x * 256 + threadIdx.x) * 4;
  float4 v = *(const float4*)(in + i);
  bf16x4 o = { (bf16)v.x, (bf16)v.y, (bf16)v.z, (bf16)v.w };
  *(bf16x4*)(out + i) = o;
}

// ---------------- W (K x N fp32) -> WT (N x K bf16) ----------------
__global__ __launch_bounds__(256) void k_twt(const float* __restrict__ W,
                                             bf16* __restrict__ WT, int K, int N) {
  __shared__ float t[64][65];
  int k0 = blockIdx.x * 64, n0 = blockIdx.y * 64;
  int r4 = threadIdx.x >> 6, c = threadIdx.x & 63;
#pragma unroll
  for (int i = 0; i < 16; i++) {
    int r = i * 4 + r4;
    t[r][c] = W[(size_t)(k0 + r) * N + n0 + c];
  }
  __syncthreads();
#pragma unroll
  for (int i = 0; i < 16; i++) {
    int r = i * 4 + r4;
    WT[(size_t)(n0 + r) * K + k0 + c] = (bf16)t[c][r];
  }
}

// ---------------- V pre-transpose: QKV V-cols -> Vtg[(b*4+kvh)*128 + d][t] ----
__global__ __launch_bounds__(256) void k_vt(const bf16* __restrict__ QKV,
                                            bf16* __restrict__ Vtg) {
  __shared__ bf16 t[64][65];
  const int t0 = blockIdx.x * 64, d0 = blockIdx.y * 64;
  const int g = blockIdx.z, b = g >> 2, kvh = g & 3;
  const bf16* src = QKV + (size_t)b * T_SEQ * NQKV + 2560 + kvh * DHEAD;
  bf16* dst = Vtg + ((size_t)(b * 4 + kvh) * 128 + d0) * T_SEQ + t0;
  const int r4 = threadIdx.x >> 6, c = threadIdx.x & 63;
#pragma unroll
  for (int i = 0; i < 16; i++) {
    int r = i * 4 + r4;
    t[r][c] = src[(size_t)(t0 + r) * NQKV + d0 + c];
  }
  __syncthreads();
#pragma unroll
  for (int i = 0; i < 16; i++) {
    int r = i * 4 + r4;
    dst[(size_t)r * T_SEQ + c] = t[c][r];
  }
}

// ---------------- GEMM: C[M,N] = A[M,K] * BT[N,K]^T  (m97 + XCD swizzle) --------
template<bool F32OUT>
__global__ __launch_bounds__(256) void k_gemm(const bf16* __restrict__ A,
                                              const bf16* __restrict__ BT,
                                              void* __restrict__ C,
                                              int M, int N, int K) {
  __shared__ __align__(16) bf16 As[128 * 64];
  __shared__ __align__(16) bf16 Bs[128 * 64];
  const int nwg = gridDim.x * gridDim.y;
  const int orig = blockIdx.y * gridDim.x + blockIdx.x;
  const int tile = (orig & 7) * (nwg >> 3) + (orig >> 3);   // nwg % 8 == 0
  const int m0 = (tile % gridDim.x) * 128, n0 = (tile / gridDim.x) * 128;
  const int tid = threadIdx.x;
  const int lane = tid & 63, w = tid >> 6;
  const int wr = w >> 1, wc = w & 1;
  const int l15 = lane & 15, lg = lane >> 4;
  f32x4 acc[4][4] = {};

  const int rA = w * 32 + (lane >> 3);
  const int cA = (lane & 7) * 8;
  const bf16* gA = A  + (size_t)(m0 + rA) * K + cA;
  const bf16* gB = BT + (size_t)(n0 + rA) * K + cA;

  for (int k0 = 0; k0 < K; k0 += 64) {
    __syncthreads();
#pragma unroll
    for (int i = 0; i < 4; i++) {
      gload_lds16(gA + (size_t)i * 8 * K + k0, As + (w * 4 + i) * 512);
      gload_lds16(gB + (size_t)i * 8 * K + k0, Bs + (w * 4 + i) * 512);
    }
    __syncthreads();
#pragma unroll
    for (int kk = 0; kk < 2; kk++) {
      bf16x8 af[4], bfr[4];
#pragma unroll
      for (int m = 0; m < 4; m++)
        af[m] = *(const bf16x8*)(As + (wr * 64 + m * 16 + l15) * 64 + kk * 32 + lg * 8);
#pragma unroll
      for (int n = 0; n < 4; n++)
        bfr[n] = *(const bf16x8*)(Bs + (wc * 64 + n * 16 + l15) * 64 + kk * 32 + lg * 8);
#pragma unroll
      for (int m = 0; m < 4; m++)
#pragma unroll
        for (int n = 0; n < 4; n++)
          acc[m][n] = __builtin_amdgcn_mfma_f32_16x16x32_bf16(af[m], bfr[n], acc[m][n], 0, 0, 0);
    }
  }
  const int r0 = m0 + wr * 64 + lg * 4;
  const int c0 = n0 + wc * 64 + l15;
#pragma unroll
  for (int m = 0; m < 4; m++)
#pragma unroll
    for (int n = 0; n < 4; n++)
#pragma unroll
      for (int i = 0; i < 4; i++) {
        size_t idx = (size_t)(r0 + m * 16 + i) * N + (c0 + n * 16);
        if (F32OUT) ((float*)C)[idx] = acc[m][n][i];
        else        ((bf16*)C)[idx]  = (bf16)acc[m][n][i];
      }
}

// ---------------- in-place RoPE on QKV cols [0,2560) ----------------
__global__ void k_rope(bf16* __restrict__ QKV) {
  const float L2B = 0.20762050593046007f;  // log2(10000)/64
  int tid = blockIdx.x * 256 + threadIdx.x;
  int row = tid / 320;
  int c8 = (tid - row * 320) * 8;
  int t = row & (T_SEQ - 1);
  bf16* p = QKV + (size_t)row * NQKV + c8;
  bf16x8 v = *(const bf16x8*)p;
  int ib = (c8 & 127) >> 1;
  bf16x8 o;
#pragma unroll
  for (int m = 0; m < 4; m++) {
    float inv = exp2f(-(float)(ib + m) * L2B);
    float ang = (float)t * inv;
    float cs, sn;
    __sincosf(ang, &sn, &cs);
    float x1 = (float)v[2 * m], x2 = (float)v[2 * m + 1];
    o[2 * m]     = (bf16)(x1 * cs - x2 * sn);
    o[2 * m + 1] = (bf16)(x1 * sn + x2 * cs);
  }
  *(bf16x8*)p = o;
}

// ---------------- flash attention (causal, GQA), paired q-tiles ----------------
// Q pre-scaled by (1/sqrt(Dh))*log2(e): softmax runs in exp2 space.
// Row-sum via extra MFMA with ones-B (no shuffle chain); defer-max THR=8.
#define COMPUTE(qreg, o, mrow, lrow, qt_this, kt, cur) do {                               \
    f32x4 s_[4] = {};                                                                     \
    const char* ks_ = (const char*)Ks[cur];                                               \
    UNROLL for (int kk = 0; kk < 4; kk++)                                                 \
      UNROLL for (int n = 0; n < 4; n++) {                                                \
        int row_ = n * 16 + l15;                                                          \
        int cb_ = (kk * 64 + lg * 16) ^ ((row_ & 7) << 4);                                \
        bf16x8 kf_ = *(const bf16x8*)(ks_ + row_ * 256 + cb_);                            \
        s_[n] = __builtin_amdgcn_mfma_f32_16x16x32_bf16(qreg[kk], kf_, s_[n], 0, 0, 0);   \
      }                                                                                   \
    if ((kt) == (qt_this)) {                                                              \
      UNROLL for (int n = 0; n < 4; n++)                                                  \
        UNROLL for (int i = 0; i < 4; i++)                                                \
          if ((kt) * 64 + n * 16 + l15 > (qt_this) * 64 + w * 16 + lg * 4 + i)            \
            s_[n][i] = -1e30f;                                                            \
    }                                                                                     \
    float pm_[4];                                                                         \
    UNROLL for (int i = 0; i < 4; i++)                                                    \
      pm_[i] = fmaxf(fmaxf(s_[0][i], s_[1][i]), fmaxf(s_[2][i], s_[3][i]));               \
    UNROLL for (int i = 0; i < 4; i++) {                                                  \
      float v_ = pm_[i];                                                                  \
      v_ = fmaxf(v_, __shfl_xor(v_, 1));                                                  \
      v_ = fmaxf(v_, __shfl_xor(v_, 2));                                                  \
      v_ = fmaxf(v_, __shfl_xor(v_, 4));                                                  \
      v_ = fmaxf(v_, __shfl_xor(v_, 8));                                                  \
      pm_[i] = v_;                                                                        \
    }                                                                                     \
    bool ok_ = true;                                                                      \
    UNROLL for (int i = 0; i < 4; i++) ok_ = ok_ && (pm_[i] <= mrow[i] + 8.0f);           \
    if (!__all(ok_)) {                                                                    \
      UNROLL for (int i = 0; i < 4; i++) {                                                \
        float mn_ = fmaxf(mrow[i], pm_[i]);                                               \
        float al_ = __builtin_amdgcn_exp2f(mrow[i] - mn_);                                \
        mrow[i] = mn_;                                                                    \
        lrow[i] *= al_;                                                                   \
        UNROLL for (int n = 0; n < 8; n++) o[n][i] *= al_;                                \
      }                                                                                   \
    }                                                                                     \
    UNROLL for (int n = 0; n < 4; n++)                                                    \
      UNROLL for (int i = 0; i < 4; i++)                                                  \
        Ps[w][lg * 4 + i][n * 16 + l15] =                                                 \
            (bf16)__builtin_amdgcn_exp2f(s_[n][i] - mrow[i]);                             \
    f32x4 rs_ = {};                                                                       \
    const char* vs_ = (const char*)Vs[cur];                                               \
    UNROLL for (int kc = 0; kc < 2; kc++) {                                               \
      bf16x8 pa_ = *(const bf16x8*)(&Ps[w][l15][kc * 32 + lg * 8]);                       \
      rs_ = __builtin_amdgcn_mfma_f32_16x16x32_bf16(pa_, ones_, rs_, 0, 0, 0);            \
      UNROLL for (int n = 0; n < 8; n++) {                                                \
        int d_ = n * 16 + l15;                                                            \
        bf16x8 vf_ = *(const bf16x8*)(vs_ + d_ * 128 + ((((kc << 2) + lg) ^ (d_ & 7)) << 4)); \
        o[n] = __builtin_amdgcn_mfma_f32_16x16x32_bf16(pa_, vf_, o[n], 0, 0, 0);          \
      }                                                                                   \
    }                                                                                     \
    UNROLL for (int i = 0; i < 4; i++) lrow[i] += rs_[i];                                 \
  } while (0)

__global__ __launch_bounds__(256) void k_flash(const bf16* __restrict__ QKV,
                                               const bf16* __restrict__ Vtg,
                                               bf16* __restrict__ AO) {
  __shared__ __align__(16) bf16 Ks[2][64 * 128];   // [kv row]*256B, chunk XOR (row&7)
  __shared__ __align__(16) bf16 Vs[2][128 * 64];   // [d row]*128B,  chunk XOR (d&7)
  __shared__ __align__(16) bf16 Ps[4][16][72];
  const int orig = blockIdx.y * 16 + blockIdx.x;   // 512 blocks
  const int tswz = ((orig & 7) << 6) | (orig >> 3);
  const int p  = tswz & 15;              // 0..15 -> q-tiles p and 31-p
  const int bh = tswz >> 4;
  const int b = bh >> 4, h = bh & 15, kvh = h >> 2;
  const int qtA = p, qtB = 31 - p;
  const int tid = threadIdx.x, lane = tid & 63, w = tid >> 6;
  const int l15 = lane & 15, lg = lane >> 4;
  const float qs = 0.12753102f;          // (1/sqrt(128)) * log2(e)

  bf16x8 qA[4], qB[4];
  {
    const size_t qoA = (size_t)(b * T_SEQ + qtA * 64 + w * 16 + l15) * NQKV + h * DHEAD;
    const size_t qoB = (size_t)(b * T_SEQ + qtB * 64 + w * 16 + l15) * NQKV + h * DHEAD;
    UNROLL for (int kk = 0; kk < 4; kk++) {
      bf16x8 a = *(const bf16x8*)(QKV + qoA + kk * 32 + lg * 8);
      bf16x8 bb = *(const bf16x8*)(QKV + qoB + kk * 32 + lg * 8);
      UNROLL for (int j = 0; j < 8; j++) {
        a[j] = (bf16)((float)a[j] * qs);
        bb[j] = (bf16)((float)bb[j] * qs);
      }
      qA[kk] = a; qB[kk] = bb;
    }
  }
  bf16x8 ones_;
  UNROLL for (int j = 0; j < 8; j++) ones_[j] = (bf16)1.0f;

  f32x4 oA[8] = {}, oB[8] = {};
  float mA[4], lAc[4], mB[4], lBc[4];
  UNROLL for (int i = 0; i < 4; i++) { mA[i] = mB[i] = -1e30f; lAc[i] = lBc[i] = 0.f; }

  const bf16* Kbase = QKV + (size_t)b * T_SEQ * NQKV + DMODEL + kvh * DHEAD;
  const bf16* Vbase = Vtg + (size_t)(b * 4 + kvh) * 128 * T_SEQ;

  auto issueK = [&](int buf, int kt) {
    UNROLL for (int i = 0; i < 4; i++) {
      int row = w * 16 + i * 4 + lg;
      int col = (l15 ^ (row & 7)) * 8;
      gload_lds16(Kbase + (size_t)(kt * 64 + row) * NQKV + col,
                  Ks[buf] + (w * 4 + i) * 512);
    }
  };
  auto issueV = [&](int buf, int kt) {
    UNROLL for (int i = 0; i < 4; i++) {
      int d = (w * 4 + i) * 8 + (lane >> 3);
      int u = lane & 7;
      gload_lds16(Vbase + (size_t)d * T_SEQ + kt * 64 + ((u ^ (d & 7)) * 8),
                  Vs[buf] + (w * 4 + i) * 512);
    }
  };

  issueK(0, 0);
  issueV(0, 0);
  __syncthreads();

  const int NT = qtB + 1;
  for (int kt = 0; kt < NT; kt++) {
    const int cur = kt & 1, nxt = cur ^ 1;
    if (kt + 1 < NT) { issueK(nxt, kt + 1); issueV(nxt, kt + 1); }
    COMPUTE(qB, oB, mB, lBc, qtB, kt, cur);
    if (kt <= qtA) COMPUTE(qA, oA, mA, lAc, qtA, kt, cur);
    __syncthreads();
  }

  {
    const size_t obase = (size_t)(b * T_SEQ + qtA * 64 + w * 16 + lg * 4) * DMODEL + h * DHEAD + l15;
    UNROLL for (int i = 0; i < 4; i++) {
      float inv = 1.0f / lAc[i];
      UNROLL for (int n = 0; n < 8; n++)
        AO[obase + (size_t)i * DMODEL + n * 16] = (bf16)(oA[n][i] * inv);
    }
  }
  {
    const size_t obase = (size_t)(b * T_SEQ + qtB * 64 + w * 16 + lg * 4) * DMODEL + h * DHEAD + l15;
    UNROLL for (int i = 0; i < 4; i++) {
      float inv = 1.0f / lBc[i];
      UNROLL for (int n = 0; n < 8; n++)
        AO[obase + (size_t)i * DMODEL + n * 16] = (bf16)(oB[n][i] * inv);
    }
  }
}

extern "C" void kernel_launch(void* const* d_in, const int* in_sizes, int n_in,
                              void* d_out, int out_size, void* d_ws, size_t ws_size,
                              hipStream_t stream) {
  const float* x  = (const float*)d_in[0];
  const float* Wq = (const float*)d_in[1];
  const float* Wk = (const float*)d_in[2];
  const float* Wv = (const float*)d_in[3];
  const float* Wo = (const float*)d_in[4];
  char* ws = (char*)d_ws;
  bf16* xb  = (bf16*)ws;                                             // 4096x2048
  bf16* WT  = (bf16*)(ws + 16777216ull);                             // 3072x2048 (WqT|WkT|WvT)
  bf16* WoT = (bf16*)(ws + 16777216ull + 12582912ull);               // 2048x2048
  bf16* QKV = (bf16*)(ws + 16777216ull + 12582912ull + 8388608ull);  // 4096x3072
  bf16* AO  = (bf16*)(ws + 16777216ull + 12582912ull + 8388608ull + 25165824ull); // 4096x2048
  bf16* Vtg = WT;   // WT is dead after the QKV GEMM; reuse first 4 MB for V^T
  float* out = (float*)d_out;

  k_cvt<<<8192, 256, 0, stream>>>(x, xb);
  k_twt<<<dim3(32, 32), 256, 0, stream>>>(Wq, WT, 2048, 2048);
  k_twt<<<dim3(32, 8), 256, 0, stream>>>(Wk, WT + (size_t)2048 * 2048, 2048, 512);
  k_twt<<<dim3(32, 8), 256, 0, stream>>>(Wv, WT + (size_t)2560 * 2048, 2048, 512);
  k_twt<<<dim3(32, 32), 256, 0, stream>>>(Wo, WoT, 2048, 2048);
  k_gemm<false><<<dim3(32, 24), 256, 0, stream>>>(xb, WT, QKV, 4096, 3072, 2048);
  k_rope<<<5120, 256, 0, stream>>>(QKV);
  k_vt<<<dim3(32, 2, 8), 256, 0, stream>>>(QKV, Vtg);
  k_flash<<<dim3(16, 32), 256, 0, stream>>>(QKV, Vtg, AO);
  k_gemm<true><<<dim3(32, 16), 256, 0, stream>>>(AO, WoT, out, 4096, 2048, 2048);
}